// Round 9
// baseline (2246.780 us; speedup 1.0000x reference)
//
#include <hip/hip_runtime.h>

typedef _Float16 f16;
typedef _Float16 f16x8 __attribute__((ext_vector_type(8)));
typedef _Float16 f16x4 __attribute__((ext_vector_type(4)));
typedef float    f32x4  __attribute__((ext_vector_type(4)));
typedef float    f32x16 __attribute__((ext_vector_type(16)));

#define NB 4
#define SEQ 4096
#define DIM 512
#define MTOT (NB*SEQ)   // 16384
#define NEL ((size_t)MTOT*DIM)

// ---------------------------------------------------------------------------
// Projection GEMM: out[m,n] = f16( sum_k A[m,k] * W[n,k] + bias[n] )
// p: 0:q natural  1:qv natural  2:k K-swizzled(32x32x16 B-frag)  3:kv V-swizzled
// K (per batch, per 32-row kv tile t, unit = 8 f16 along d, 64 units/row):
//   unit = t*2048 + kv*64 + ((du + kv) & 63), elem j;  kv = s&31, du = d>>3
//   -> attn reads B[k=d][n=kv]: lane(col=kv=lane&31, hi=lane>>5) reads unit
//      kv*64 + ((st*2+hi+kv)&63): bank phase (st*2+hi+kv)%8 distinct per 8 lanes.
// V (R4-proven): unit = t*2048 + chunk*1024 + dl*4 + ((q+(dl>>1))&3), elem j
//   where s = t*32 + q*8 + j, dl = d&255, chunk = d>>8
// ---------------------------------------------------------------------------
__global__ __launch_bounds__(256) void proj_gemm(
    const float* __restrict__ x, const float* __restrict__ y,
    const float* __restrict__ Wq, const float* __restrict__ bq,
    const float* __restrict__ Wqv, const float* __restrict__ bqv,
    const float* __restrict__ Wk, const float* __restrict__ bk,
    const float* __restrict__ Wkv, const float* __restrict__ bkv,
    f16* __restrict__ qh, f16* __restrict__ qvh,
    f16* __restrict__ kS, f16* __restrict__ vS)
{
    __shared__ __attribute__((aligned(16))) f16 a_lds[128][40];
    __shared__ __attribute__((aligned(16))) f16 b_lds[128][40];

    const int p = blockIdx.z;
    const float* A    = (p < 2) ? x : y;
    const float* W    = (p==0)?Wq:(p==1)?Wqv:(p==2)?Wk:Wkv;
    const float* bias = (p==0)?bq:(p==1)?bqv:(p==2)?bk:bkv;

    const int m0 = blockIdx.y * 128, n0 = blockIdx.x * 128;
    const int tid = threadIdx.x, lane = tid & 63, wv = tid >> 6;
    const int wm = wv >> 1, wn = wv & 1, mrow = lane & 15, qd = lane >> 4;

    f32x4 acc[4][4];
#pragma unroll
    for (int mt = 0; mt < 4; ++mt)
#pragma unroll
        for (int nt = 0; nt < 4; ++nt) acc[mt][nt] = (f32x4){0.f,0.f,0.f,0.f};

    float bv[4];
#pragma unroll
    for (int nt = 0; nt < 4; ++nt) bv[nt] = bias[n0 + wn*64 + nt*16 + mrow];

    for (int k0 = 0; k0 < DIM; k0 += 32) {
        __syncthreads();
#pragma unroll
        for (int i = 0; i < 4; ++i) {
            int c = i*256 + tid;
            int row = c >> 3, c4 = c & 7;
            float4 v = *(const float4*)(A + (size_t)(m0+row)*DIM + k0 + c4*4);
            f16x4 hh = { (f16)v.x, (f16)v.y, (f16)v.z, (f16)v.w };
            *(f16x4*)&a_lds[row][c4*4] = hh;
        }
#pragma unroll
        for (int i = 0; i < 4; ++i) {
            int c = i*256 + tid;
            int row = c >> 3, c4 = c & 7;
            float4 v = *(const float4*)(W + (size_t)(n0+row)*DIM + k0 + c4*4);
            f16x4 hh = { (f16)v.x, (f16)v.y, (f16)v.z, (f16)v.w };
            *(f16x4*)&b_lds[row][c4*4] = hh;
        }
        __syncthreads();
        f16x8 af[4], bfr[4];
#pragma unroll
        for (int mt = 0; mt < 4; ++mt) af[mt]  = *(const f16x8*)&a_lds[wm*64 + mt*16 + mrow][qd*8];
#pragma unroll
        for (int nt = 0; nt < 4; ++nt) bfr[nt] = *(const f16x8*)&b_lds[wn*64 + nt*16 + mrow][qd*8];
#pragma unroll
        for (int mt = 0; mt < 4; ++mt)
#pragma unroll
            for (int nt = 0; nt < 4; ++nt)
                acc[mt][nt] = __builtin_amdgcn_mfma_f32_16x16x32_f16(af[mt], bfr[nt], acc[mt][nt], 0,0,0);
    }

#pragma unroll
    for (int mt = 0; mt < 4; ++mt)
#pragma unroll
        for (int r = 0; r < 4; ++r) {
            int g = m0 + wm*64 + mt*16 + qd*4 + r;
#pragma unroll
            for (int nt = 0; nt < 4; ++nt) {
                int d = n0 + wn*64 + nt*16 + mrow;
                f16 val = (f16)(acc[mt][nt][r] + bv[nt]);
                if (p == 0) {
                    qh[(size_t)g*DIM + d] = val;
                } else if (p == 1) {
                    qvh[(size_t)g*DIM + d] = val;
                } else if (p == 2) {
                    int b = g >> 12, s = g & 4095;
                    int t = s >> 5, kv = s & 31;
                    int du = d >> 3, j = d & 7;
                    size_t idx = (((size_t)((b*128 + t)*2048
                                   + kv*64 + ((du + kv) & 63))) << 3) + j;
                    kS[idx] = val;
                } else {
                    int b = g >> 12, s = g & 4095;
                    int t = s >> 5, q = (s >> 3) & 3, j = s & 7;
                    int chunk = d >> 8, dl = d & 255;
                    size_t idx = (((size_t)((b*128 + t)*2048 + chunk*1024
                                   + dl*4 + ((q + (dl >> 1)) & 3))) << 3) + j;
                    vS[idx] = val;
                }
            }
        }
}

// ---------------------------------------------------------------------------
// Flash attention: 32x32x16 MFMA, 32 q-rows x full D per wave.
// Grid 256 x 256thr (proven config); xcd=bx&7 -> (b=xcd>>1, h=xcd&1):
// per-XCD unique KV = 4MB, L2-resident, drift-immune. Block = 128 q-rows,
// half KV = 64 iters of 32-row tiles, single-buffer sync staging from L2.
// Registers: O=256 AGPR (exact), Q=128 VGPR, no prefetch regs -> no spill.
// ---------------------------------------------------------------------------
__global__ __launch_bounds__(256, 1) void attn_kernel(
    const f16* __restrict__ qh, const f16* __restrict__ kS,
    const f16* __restrict__ vS, f16* __restrict__ opart,
    float* __restrict__ ml)
{
    __shared__ __attribute__((aligned(16))) f16 kbuf[16384];      // 32KB
    __shared__ __attribute__((aligned(16))) f16 vbuf[16384];      // 32KB
    __shared__ __attribute__((aligned(16))) f16 p_lds[4][32][40]; // 10.2KB

    const int bx  = blockIdx.x;
    const int xcd = bx & 7;
    const int b   = xcd >> 1;
    const int h   = xcd & 1;
    const int qt  = bx >> 3;                 // 0..31 (128-row q tile)
    const int tid = threadIdx.x, lane = tid & 63, w = tid >> 6;
    const int col = lane & 31, hi = lane >> 5;

    const f16* kSb = kS + ((size_t)b << 21) + ((size_t)h << 20);
    const f16* vSb = vS + ((size_t)b << 21) + ((size_t)h << 20);

    // Q A-frags (32x32x16): lane holds Q[qbase+col][st*16 + hi*8 + j]
    const int qrow_l = b*SEQ + qt*128 + w*32 + col;
    f16x8 qf[32];
#pragma unroll
    for (int st = 0; st < 32; ++st)
        qf[st] = *(const f16x8*)(qh + (size_t)qrow_l*DIM + st*16 + hi*8);

    f32x16 o[16];
#pragma unroll
    for (int dt = 0; dt < 16; ++dt)
#pragma unroll
        for (int r = 0; r < 16; ++r) o[dt][r] = 0.f;
    float m_i[16], l_i[16];
#pragma unroll
    for (int r = 0; r < 16; ++r) { m_i[r] = -INFINITY; l_i[r] = 0.f; }

    for (int i = 0; i < 64; ++i) {
        // sync staging from L2 (KV half is L2-resident after first sweep)
        const f16* kt = kSb + (size_t)i*16384;
        const f16* vt = vSb + (size_t)i*16384;
        f16x8 sk[8], sv[8];
#pragma unroll
        for (int j = 0; j < 8; ++j) {
            sk[j] = *(const f16x8*)(kt + (j*256 + tid)*8);
            sv[j] = *(const f16x8*)(vt + (j*256 + tid)*8);
        }
        __syncthreads();   // readers of tile i-1 done
#pragma unroll
        for (int j = 0; j < 8; ++j) {
            *(f16x8*)&kbuf[(j*256 + tid)*8] = sk[j];
            *(f16x8*)&vbuf[(j*256 + tid)*8] = sv[j];
        }
        __syncthreads();

        // S = Q K^T : one 32x32 tile per wave, 32 k-steps of 16
        f32x16 S;
#pragma unroll
        for (int r = 0; r < 16; ++r) S[r] = 0.f;
#pragma unroll
        for (int st = 0; st < 32; ++st) {
            f16x8 kf = *(const f16x8*)&kbuf[(col*64 + ((st*2 + hi + col) & 63)) << 3];
            S = __builtin_amdgcn_mfma_f32_32x32x16_f16(qf[st], kf, S, 0,0,0);
        }

        // online softmax: reg r holds row (r&3)+8*(r>>2)+4*hi, col=lane&31
        float alpha[16];
        bool changed = false;
#pragma unroll
        for (int r = 0; r < 16; ++r) {
            float v = S[r];
            v = fmaxf(v, __shfl_xor(v, 1));
            v = fmaxf(v, __shfl_xor(v, 2));
            v = fmaxf(v, __shfl_xor(v, 4));
            v = fmaxf(v, __shfl_xor(v, 8));
            v = fmaxf(v, __shfl_xor(v, 16));
            float mn = fmaxf(m_i[r], v);
            alpha[r] = __expf(m_i[r] - mn);
            if (mn > m_i[r]) changed = true;
            m_i[r] = mn;
            float pv = __expf(S[r] - mn);
            S[r] = pv;
            float rs = pv;
            rs += __shfl_xor(rs, 1);
            rs += __shfl_xor(rs, 2);
            rs += __shfl_xor(rs, 4);
            rs += __shfl_xor(rs, 8);
            rs += __shfl_xor(rs, 16);
            l_i[r] = l_i[r]*alpha[r] + rs;
        }
        if (__any(changed)) {
#pragma unroll
            for (int dt = 0; dt < 16; ++dt)
#pragma unroll
                for (int r = 0; r < 16; ++r) o[dt][r] *= alpha[r];
        }

        // P: C-layout -> A-layout via per-wave LDS (intra-wave, in-order)
#pragma unroll
        for (int r = 0; r < 16; ++r)
            p_lds[w][(r & 3) + 8*(r >> 2) + 4*hi][col] = (f16)S[r];
        f16x8 pf0 = *(const f16x8*)&p_lds[w][col][hi*8];
        f16x8 pf1 = *(const f16x8*)&p_lds[w][col][16 + hi*8];

        // O += P @ V : 16 d-tiles of 32 cols, 2 k-steps of 16 kv
#pragma unroll
        for (int dt = 0; dt < 16; ++dt) {
            int d = dt*32 + col;
            int chunk = d >> 8, dl = d & 255;
            f16x8 vf0 = *(const f16x8*)&vbuf[(chunk*1024 + dl*4 + ((hi     + (dl >> 1)) & 3)) << 3];
            f16x8 vf1 = *(const f16x8*)&vbuf[(chunk*1024 + dl*4 + ((2 + hi + (dl >> 1)) & 3)) << 3];
            o[dt] = __builtin_amdgcn_mfma_f32_32x32x16_f16(pf0, vf0, o[dt], 0,0,0);
            o[dt] = __builtin_amdgcn_mfma_f32_32x32x16_f16(pf1, vf1, o[dt], 0,0,0);
        }
    }

    // epilogue: normalized partial O + (m,l)
    float inv_l[16];
#pragma unroll
    for (int r = 0; r < 16; ++r) inv_l[r] = 1.f / l_i[r];
#pragma unroll
    for (int dt = 0; dt < 16; ++dt) {
#pragma unroll
        for (int r = 0; r < 16; ++r) {
            int row = (r & 3) + 8*(r >> 2) + 4*hi;
            size_t grow = ((size_t)(b*SEQ + qt*128 + w*32 + row))*DIM + dt*32 + col;
            opart[(size_t)h*NEL + grow] = (f16)(o[dt][r] * inv_l[r]);
        }
    }
    if (col == 0) {
#pragma unroll
        for (int r = 0; r < 16; ++r) {
            int row = (r & 3) + 8*(r >> 2) + 4*hi;
            int idx = h*MTOT + b*SEQ + qt*128 + w*32 + row;
            ml[idx*2 + 0] = m_i[r];
            ml[idx*2 + 1] = l_i[r];
        }
    }
}

// ---------------------------------------------------------------------------
// Merge the two kv-half partials (LSE-weighted) + qv residual -> ao (f16)
// ---------------------------------------------------------------------------
__global__ __launch_bounds__(256) void merge_kernel(
    const f16* __restrict__ opart, const float* __restrict__ ml,
    const f16* __restrict__ qvh, f16* __restrict__ ao)
{
    int gid = blockIdx.x * 256 + threadIdx.x;
    int row = gid >> 6;
    int dc  = (gid & 63) * 8;
    float m1 = ml[row*2 + 0],           l1 = ml[row*2 + 1];
    float m2 = ml[(row + MTOT)*2 + 0],  l2 = ml[(row + MTOT)*2 + 1];
    float mm = fmaxf(m1, m2);
    float w1 = __expf(m1 - mm) * l1, w2 = __expf(m2 - mm) * l2;
    float il = 1.f / (w1 + w2);
    w1 *= il; w2 *= il;
    f16x8 o1 = *(const f16x8*)(opart + (size_t)row*DIM + dc);
    f16x8 o2 = *(const f16x8*)(opart + NEL + (size_t)row*DIM + dc);
    f16x8 qv = *(const f16x8*)(qvh + (size_t)row*DIM + dc);
    f16x8 r;
#pragma unroll
    for (int j = 0; j < 8; ++j)
        r[j] = (f16)(w1*(float)o1[j] + w2*(float)o2[j] + (float)qv[j]);
    *(f16x8*)(ao + (size_t)row*DIM + dc) = r;
}

// ---------------------------------------------------------------------------
// Final linear: out[m,n] = sum_k ao[m,k]*Wf[n,k] + bf[n]  (f32 out)
// ---------------------------------------------------------------------------
__global__ __launch_bounds__(256) void final_gemm(
    const f16* __restrict__ ao, const float* __restrict__ Wf,
    const float* __restrict__ bf, float* __restrict__ out)
{
    __shared__ __attribute__((aligned(16))) f16 a_lds[128][40];
    __shared__ __attribute__((aligned(16))) f16 b_lds[128][40];

    const int m0 = blockIdx.y * 128, n0 = blockIdx.x * 128;
    const int tid = threadIdx.x, lane = tid & 63, wv = tid >> 6;
    const int wm = wv >> 1, wn = wv & 1, mrow = lane & 15, qd = lane >> 4;

    f32x4 acc[4][4];
#pragma unroll
    for (int mt = 0; mt < 4; ++mt)
#pragma unroll
        for (int nt = 0; nt < 4; ++nt) acc[mt][nt] = (f32x4){0.f,0.f,0.f,0.f};

    float bv[4];
#pragma unroll
    for (int nt = 0; nt < 4; ++nt) bv[nt] = bf[n0 + wn*64 + nt*16 + mrow];

    for (int k0 = 0; k0 < DIM; k0 += 32) {
        __syncthreads();
#pragma unroll
        for (int i = 0; i < 2; ++i) {
            int c = i*256 + tid;
            int row = c >> 2, c8 = c & 3;
            *(f16x8*)&a_lds[row][c8*8] =
                *(const f16x8*)(ao + (size_t)(m0+row)*DIM + k0 + c8*8);
        }
#pragma unroll
        for (int i = 0; i < 4; ++i) {
            int c = i*256 + tid;
            int row = c >> 3, c4 = c & 7;
            float4 v = *(const float4*)(Wf + (size_t)(n0+row)*DIM + k0 + c4*4);
            f16x4 hh = { (f16)v.x, (f16)v.y, (f16)v.z, (f16)v.w };
            *(f16x4*)&b_lds[row][c4*4] = hh;
        }
        __syncthreads();
        f16x8 af[4], bfr[4];
#pragma unroll
        for (int mt = 0; mt < 4; ++mt) af[mt]  = *(const f16x8*)&a_lds[wm*64 + mt*16 + mrow][qd*8];
#pragma unroll
        for (int nt = 0; nt < 4; ++nt) bfr[nt] = *(const f16x8*)&b_lds[wn*64 + nt*16 + mrow][qd*8];
#pragma unroll
        for (int mt = 0; mt < 4; ++mt)
#pragma unroll
            for (int nt = 0; nt < 4; ++nt)
                acc[mt][nt] = __builtin_amdgcn_mfma_f32_16x16x32_f16(af[mt], bfr[nt], acc[mt][nt], 0,0,0);
    }
#pragma unroll
    for (int mt = 0; mt < 4; ++mt)
#pragma unroll
        for (int r = 0; r < 4; ++r) {
            size_t grow = (size_t)(m0 + wm*64 + mt*16 + qd*4 + r) * DIM;
#pragma unroll
            for (int nt = 0; nt < 4; ++nt) {
                int col = n0 + wn*64 + nt*16 + mrow;
                out[grow + col] = acc[mt][nt][r] + bv[nt];
            }
        }
}

// ---------------------------------------------------------------------------
extern "C" void kernel_launch(void* const* d_in, const int* in_sizes, int n_in,
                              void* d_out, int out_size, void* d_ws, size_t ws_size,
                              hipStream_t stream)
{
    const float* x   = (const float*)d_in[0];
    const float* y   = (const float*)d_in[1];
    const float* Wq  = (const float*)d_in[2];
    const float* bq  = (const float*)d_in[3];
    const float* Wqv = (const float*)d_in[4];
    const float* bqv = (const float*)d_in[5];
    const float* Wk  = (const float*)d_in[6];
    const float* bk  = (const float*)d_in[7];
    const float* Wkv = (const float*)d_in[8];
    const float* bkv = (const float*)d_in[9];
    const float* Wf  = (const float*)d_in[10];
    const float* bf  = (const float*)d_in[11];
    float* out = (float*)d_out;

    f16* qh    = (f16*)d_ws;       // NEL f16 each
    f16* qvh   = qh  + NEL;
    f16* kS    = qvh + NEL;
    f16* vS    = kS  + NEL;
    f16* opart = vS  + NEL;        // 2*NEL
    float* ml  = (float*)(opart + 2*NEL);  // 2*MTOT*2 floats
    f16* aob   = kS;               // alias: kS dead after attn_kernel

    proj_gemm<<<dim3(4, 128, 4), 256, 0, stream>>>(
        x, y, Wq, bq, Wqv, bqv, Wk, bk, Wkv, bkv, qh, qvh, kS, vS);
    attn_kernel<<<dim3(256), 256, 0, stream>>>(qh, kS, vS, opart, ml);
    merge_kernel<<<dim3(4096), 256, 0, stream>>>(opart, ml, qvh, aob);
    final_gemm<<<dim3(4, 128), 256, 0, stream>>>(aob, Wf, bf, out);
}